// Round 1
// baseline (406.764 us; speedup 1.0000x reference)
//
#include <hip/hip_runtime.h>
#include <stdint.h>

// ---------------------------------------------------------------------------
// AvgClicksPoolingInitializer  (B=8, I=16, C=256)
// Levels: L=0..3  w=128>>L, P=w*w, k=4<<L (scribble 512 / w)
// Bilinear half-pixel downsample 512->w lands exactly between two pixels in
// each dim => m[y][x] = 0.25*(S[r0][c0]+S[r0][c1]+S[r1][c0]+S[r1][c1]),
// r0 = k*y + k/2 - 1, c0 = k*x + k/2 - 1.   sel = (m > 0.5)  <=>  sum4 > 2.0
// ---------------------------------------------------------------------------

#define NI 16
#define NB 8
#define NC 256
#define PTOT 21760   // 16384+4096+1024+256

__device__ __forceinline__ int level_off(int L) {
    return (L == 0) ? 0 : (L == 1) ? 16384 : (L == 2) ? 20480 : 21504;
}

__device__ __forceinline__ unsigned long long shfl_down_u64(unsigned long long v, int off) {
    unsigned int lo = (unsigned int)v;
    unsigned int hi = (unsigned int)(v >> 32);
    lo = __shfl_down(lo, off, 64);
    hi = __shfl_down(hi, off, 64);
    return ((unsigned long long)hi << 32) | lo;
}

// ---------------------------------------------------------------------------
// Kernel A: per (level, b, 256-pixel chunk) compute 16-instance sel bitmask,
// per-(b,i) count (atomicAdd) and argmax key (atomicMax, first-index tiebreak)
// ---------------------------------------------------------------------------
__global__ __launch_bounds__(256) void mask_kernel(
        const float* __restrict__ scr,          // (8,16,512,512)
        unsigned short* __restrict__ selmask,   // (8, PTOT)
        unsigned long long* __restrict__ keyw,  // (4,8,16)
        unsigned int* __restrict__ cntw) {      // (4,8,16)
    const int L = blockIdx.z, b = blockIdx.y;
    const int wl2 = 7 - L;
    const int w = 1 << wl2;
    const int P = 1 << (2 * wl2);
    const int k = 4 << L;
    const int p = blockIdx.x * 256 + threadIdx.x;
    if (p >= P) return;                         // P is a multiple of 256: whole block exits
    const int y = p >> wl2, x = p & (w - 1);
    const int r0 = k * y + (k >> 1) - 1;
    const int c0 = k * x + (k >> 1) - 1;
    const float* Sb = scr + (size_t)b * NI * 262144;
    const int lane = threadIdx.x & 63, wv = threadIdx.x >> 6;

    __shared__ unsigned long long skey[4][NI];
    __shared__ unsigned int scnt[4][NI];

    unsigned int mask = 0;
#pragma unroll
    for (int i = 0; i < NI; ++i) {
        const float* Si = Sb + (size_t)i * 262144 + r0 * 512 + c0;
        float v;
        if (k == 4) {
            // c0 = 4x+1: aligned float4 at 4x covers cols {4x..4x+3}; need .y,.z
            const float4 t0 = *(const float4*)(Si - 1);
            const float4 t1 = *(const float4*)(Si - 1 + 512);
            v = (t0.y + t0.z) + (t1.y + t1.z);
        } else {
            v = (Si[0] + Si[1]) + (Si[512] + Si[513]);
        }
        const bool sel = v > 2.0f;
        mask |= sel ? (1u << i) : 0u;

        // argmax key: value bits (v>=0 so uint-monotonic), tie -> smaller p wins
        unsigned long long key = ((unsigned long long)__float_as_uint(v) << 32)
                               | (unsigned long long)(0xFFFFFFFFu - (unsigned int)p);
#pragma unroll
        for (int off = 32; off > 0; off >>= 1) {
            unsigned long long o = shfl_down_u64(key, off);
            if (o > key) key = o;
        }
        unsigned long long bal = __ballot(sel);
        if (lane == 0) {
            skey[wv][i] = key;
            scnt[wv][i] = (unsigned int)__popcll(bal);
        }
    }
    selmask[(size_t)b * PTOT + level_off(L) + p] = (unsigned short)mask;

    __syncthreads();
    if (threadIdx.x < NI) {
        const int i = threadIdx.x;
        unsigned long long kk = skey[0][i];
        unsigned int cc = scnt[0][i];
#pragma unroll
        for (int wq = 1; wq < 4; ++wq) {
            if (skey[wq][i] > kk) kk = skey[wq][i];
            cc += scnt[wq][i];
        }
        atomicMax(&keyw[(L * NB + b) * NI + i], kk);
        atomicAdd(&cntw[(L * NB + b) * NI + i], cc);
    }
}

// ---------------------------------------------------------------------------
// Kernel B: s[L][b][i][c] = sum_p bit(i,p) * f[b][c][p]
// one wave per (b, c, L); float4 feature loads + ushort4 mask loads
// ---------------------------------------------------------------------------
__global__ __launch_bounds__(256) void pool_kernel(
        const float* __restrict__ f0, const float* __restrict__ f1,
        const float* __restrict__ f2, const float* __restrict__ f3,
        const unsigned short* __restrict__ selmask,
        float* __restrict__ sw) {               // (4,8,16,256)
    const int L = blockIdx.z, b = blockIdx.y;
    const int wl2 = 7 - L;
    const int P = 1 << (2 * wl2);
    const int lane = threadIdx.x & 63, wv = threadIdx.x >> 6;
    const int c = blockIdx.x * 4 + wv;
    const float* fL = (L == 0) ? f0 : (L == 1) ? f1 : (L == 2) ? f2 : f3;
    const float4* frow = (const float4*)(fL + (size_t)(b * NC + c) * P);
    const ushort4* srow = (const ushort4*)(selmask + (size_t)b * PTOT + level_off(L));

    float acc[NI];
#pragma unroll
    for (int i = 0; i < NI; ++i) acc[i] = 0.0f;

    const int iters = P >> 8;                   // each wave covers 256 elems/iter
    for (int it = 0; it < iters; ++it) {
        const int e = it * 64 + lane;
        const float4 fv = frow[e];
        const ushort4 mv = srow[e];
        {
            const float f = fv.x; const unsigned int m = mv.x;
#pragma unroll
            for (int i = 0; i < NI; ++i) acc[i] = fmaf((float)((m >> i) & 1u), f, acc[i]);
        }
        {
            const float f = fv.y; const unsigned int m = mv.y;
#pragma unroll
            for (int i = 0; i < NI; ++i) acc[i] = fmaf((float)((m >> i) & 1u), f, acc[i]);
        }
        {
            const float f = fv.z; const unsigned int m = mv.z;
#pragma unroll
            for (int i = 0; i < NI; ++i) acc[i] = fmaf((float)((m >> i) & 1u), f, acc[i]);
        }
        {
            const float f = fv.w; const unsigned int m = mv.w;
#pragma unroll
            for (int i = 0; i < NI; ++i) acc[i] = fmaf((float)((m >> i) & 1u), f, acc[i]);
        }
    }

#pragma unroll
    for (int i = 0; i < NI; ++i) {
        float a = acc[i];
#pragma unroll
        for (int off = 32; off > 0; off >>= 1) a += __shfl_down(a, off, 64);
        if (lane == 0) sw[((size_t)(L * NB + b) * NI + i) * NC + c] = a;
    }
}

// ---------------------------------------------------------------------------
// Kernel C: out[b][i][c] = 0.25 * sum_L (cnt>0 ? s/cnt : f[b][c][argmax])
// ---------------------------------------------------------------------------
__global__ __launch_bounds__(256) void final_kernel(
        const float* __restrict__ f0, const float* __restrict__ f1,
        const float* __restrict__ f2, const float* __restrict__ f3,
        const float* __restrict__ sw,
        const unsigned int* __restrict__ cntw,
        const unsigned long long* __restrict__ keyw,
        float* __restrict__ out) {
    const int n = blockIdx.x * 256 + threadIdx.x;   // 32768 total
    const int c = n & 255;
    const int bi = n >> 8;
    const int i = bi & (NI - 1);
    const int b = bi >> 4;
    float acc = 0.0f;
#pragma unroll
    for (int L = 0; L < 4; ++L) {
        const unsigned int cc = cntw[(L * NB + b) * NI + i];
        if (cc > 0) {
            acc += sw[((size_t)(L * NB + b) * NI + i) * NC + c] / (float)cc;
        } else {
            const unsigned long long kk = keyw[(L * NB + b) * NI + i];
            const unsigned int p = 0xFFFFFFFFu - (unsigned int)(kk & 0xFFFFFFFFull);
            const float* fL = (L == 0) ? f0 : (L == 1) ? f1 : (L == 2) ? f2 : f3;
            const int P = 16384 >> (2 * L);
            acc += fL[(size_t)(b * NC + c) * P + p];
        }
    }
    out[n] = acc * 0.25f;
}

extern "C" void kernel_launch(void* const* d_in, const int* in_sizes, int n_in,
                              void* d_out, int out_size, void* d_ws, size_t ws_size,
                              hipStream_t stream) {
    (void)in_sizes; (void)n_in; (void)out_size; (void)ws_size;
    const float* f0  = (const float*)d_in[0];   // (8,256,128,128)
    const float* f1  = (const float*)d_in[1];   // (8,256,64,64)
    const float* f2  = (const float*)d_in[2];   // (8,256,32,32)
    const float* f3  = (const float*)d_in[3];   // (8,256,16,16)
    const float* scr = (const float*)d_in[4];   // (8,16,512,512)
    float* out = (float*)d_out;                 // (8,16,256) fp32

    char* ws = (char*)d_ws;
    float*              sww  = (float*)ws;                              // 524288 B
    unsigned long long* keyw = (unsigned long long*)(ws + 524288);      //   4096 B
    unsigned int*       cntw = (unsigned int*)(ws + 528384);            //   2048 B
    unsigned short*     selm = (unsigned short*)(ws + 530432);          // 348160 B

    // zero argmax keys + counts (ws is poisoned to 0xAA before every call)
    hipMemsetAsync(ws + 524288, 0, 4096 + 2048, stream);

    dim3 gA(64, NB, 4);
    mask_kernel<<<gA, 256, 0, stream>>>(scr, selm, keyw, cntw);

    dim3 gB(NC / 4, NB, 4);
    pool_kernel<<<gB, 256, 0, stream>>>(f0, f1, f2, f3, selm, sww);

    final_kernel<<<128, 256, 0, stream>>>(f0, f1, f2, f3, sww, cntw, keyw, out);
}